// Round 24
// baseline (152.604 us; speedup 1.0000x reference)
//
#include <hip/hip_runtime.h>
#include <hip/hip_bf16.h>

// GCNConv: one-pass fixed-capacity binning (64 tgts/bucket, CAP slots each) ->
// fused per-half-bucket {LDS counting sort + node-pair quarter-lane gather +
// epilogue}. No fp32 global atomics anywhere.
// agg[c] = dinv[c] * ( xs[c] + sum_{e: col[e]==c} xs[row[e]] ),
//   xs[i] = (x@W)[i] * dinv[i],  dinv[i] = rsqrt(1 + indeg(i))
// out = dropout(tanh(agg + b)), JAX partitionable-threefry key (0,42), p_keep=0.9:
//   bits[p] = o0^o1 of threefry((0,42), 0, p); u = bitcast(bits>>9|0x3f800000)-1; keep = u<0.9.
//
// R8: __shfl only in uniform regions (predicated regions contain loads only).
// R23 discovery: k_xw was ~54us all along (6.1 waves/CU, unroll-1 serial
//   latency chains; scalarization itself worked, SGPR=112). R24 = R22 base +
//   (a) k_xw 2 waves/block k-split (12.2 waves/CU, half chain) + unroll 4;
//   (b) R23's single-pass register-cached p1 (64-tgt buckets).
//
// ws (~20.5 MB): xsh bf16[NN*64] | packed u32[NBUCK*CAP] | gcur i32[NBUCK] |
//                gspill i32[1] | spill_pk u32[SPILLCAP] | spill_bk u32[SPILLCAP] |
//                deg_g i32[NN]

#define NN 100000
#define NE 1600000
#define NBUCK 1563          // 64 tgts/bucket; bucket = tgt>>6
#define P1B 256
#define P1T 1024
#define CHUNK 6250          // P1B * CHUNK == NE
#define NSLOT 7             // ceil(CHUNK/P1T) register slots per thread
#define CAP 1152            // per-bucket region (mean 1024, +4 sigma)
#define SPILLCAP 16384
#define HCAP 1536           // per-half-bucket LDS sort capacity

// ---------------- Threefry2x32 (JAX-exact) ----------------
__device__ __forceinline__ unsigned rotl32(unsigned x, int r) {
    return (x << r) | (x >> (32 - r));
}

__device__ __forceinline__ void threefry2x32(unsigned k0, unsigned k1,
                                             unsigned x0, unsigned x1,
                                             unsigned& o0, unsigned& o1) {
    const unsigned ks0 = k0, ks1 = k1, ks2 = k0 ^ k1 ^ 0x1BD11BDAu;
    x0 += ks0; x1 += ks1;
    x0 += x1; x1 = rotl32(x1, 13); x1 ^= x0;
    x0 += x1; x1 = rotl32(x1, 15); x1 ^= x0;
    x0 += x1; x1 = rotl32(x1, 26); x1 ^= x0;
    x0 += x1; x1 = rotl32(x1, 6);  x1 ^= x0;
    x0 += ks1; x1 += ks2 + 1u;
    x0 += x1; x1 = rotl32(x1, 17); x1 ^= x0;
    x0 += x1; x1 = rotl32(x1, 29); x1 ^= x0;
    x0 += x1; x1 = rotl32(x1, 16); x1 ^= x0;
    x0 += x1; x1 = rotl32(x1, 24); x1 ^= x0;
    x0 += ks2; x1 += ks0 + 2u;
    x0 += x1; x1 = rotl32(x1, 13); x1 ^= x0;
    x0 += x1; x1 = rotl32(x1, 15); x1 ^= x0;
    x0 += x1; x1 = rotl32(x1, 26); x1 ^= x0;
    x0 += x1; x1 = rotl32(x1, 6);  x1 ^= x0;
    x0 += ks0; x1 += ks1 + 3u;
    x0 += x1; x1 = rotl32(x1, 17); x1 ^= x0;
    x0 += x1; x1 = rotl32(x1, 29); x1 ^= x0;
    x0 += x1; x1 = rotl32(x1, 16); x1 ^= x0;
    x0 += x1; x1 = rotl32(x1, 24); x1 ^= x0;
    x0 += ks1; x1 += ks2 + 4u;
    x0 += x1; x1 = rotl32(x1, 13); x1 ^= x0;
    x0 += x1; x1 = rotl32(x1, 15); x1 ^= x0;
    x0 += x1; x1 = rotl32(x1, 26); x1 ^= x0;
    x0 += x1; x1 = rotl32(x1, 6);  x1 ^= x0;
    x0 += ks2; x1 += ks0 + 5u;
    o0 = x0; o1 = x1;
}

// Per-node epilogue: quarter-reduce, redistribute, tanh + threefry dropout.
// Contains shfls — call ONLY under wave-uniform control flow.
__device__ __forceinline__ void sagg_finish(float4 a0, float4 a1, int lane,
                                            int c, float dv, float bv,
                                            float* __restrict__ out) {
    float ax = a0.x + a1.x, ay = a0.y + a1.y;
    float az = a0.z + a1.z, aw = a0.w + a1.w;
    ax += __shfl_xor(ax, 16); ax += __shfl_xor(ax, 32);
    ay += __shfl_xor(ay, 16); ay += __shfl_xor(ay, 32);
    az += __shfl_xor(az, 16); az += __shfl_xor(az, 32);
    aw += __shfl_xor(aw, 16); aw += __shfl_xor(aw, 32);
    const float sx = __shfl(ax, lane >> 2);
    const float sy = __shfl(ay, lane >> 2);
    const float sz = __shfl(az, lane >> 2);
    const float sw = __shfl(aw, lane >> 2);
    const float ab = (lane & 1) ? sy : sx;
    const float cd = (lane & 1) ? sw : sz;
    const float a = (lane & 2) ? cd : ab;
    const int p = c * 64 + lane;
    unsigned o0, o1;
    threefry2x32(0u, 42u, 0u, (unsigned)p, o0, o1);
    const unsigned bits = o0 ^ o1;
    const float u = __uint_as_float((bits >> 9) | 0x3f800000u) - 1.0f;
    const float h = tanhf(dv * a + bv);
    out[p] = (u < 0.9f) ? h / 0.9f : 0.0f;
}

#define UNPK4(v, A)                                                    \
    A.x += __uint_as_float((v).x << 16);                               \
    A.y += __uint_as_float((v).x & 0xffff0000u);                       \
    A.z += __uint_as_float((v).y << 16);                               \
    A.w += __uint_as_float((v).y & 0xffff0000u);

// ---------------- Kernels ----------------
// One-pass binning: edges register-cached during LDS hist, one global reserve
// atomic per (block,bucket), grouped writes into fixed regions, spill overflow.
__global__ __launch_bounds__(P1T) void k_p1(const int* __restrict__ ei,
                                            int* __restrict__ gcur,
                                            unsigned* __restrict__ packed,
                                            unsigned* __restrict__ spill_pk,
                                            unsigned* __restrict__ spill_bk,
                                            int* __restrict__ gspill) {
    __shared__ int hb[NBUCK];
    __shared__ int lc[NBUCK];
    const int tid = threadIdx.x;
    for (int i = tid; i < NBUCK; i += P1T) { hb[i] = 0; lc[i] = 0; }
    __syncthreads();
    const int base = blockIdx.x * CHUNK;
    unsigned tc[NSLOT], sc[NSLOT];   // register-cached edges (static idx)
#pragma unroll
    for (int k = 0; k < NSLOT; ++k) {
        const int i = tid + k * P1T;
        tc[k] = 0xFFFFFFFFu;
        sc[k] = 0u;
        if (i < CHUNK) {
            const unsigned t = (unsigned)ei[NE + base + i];
            tc[k] = t;
            sc[k] = (unsigned)ei[base + i];
            if (t < NN) atomicAdd(&hb[t >> 6], 1);
        }
    }
    __syncthreads();
    for (int i = tid; i < NBUCK; i += P1T) {
        const int h = hb[i];
        hb[i] = h ? atomicAdd(&gcur[i], h) : 0;  // reserve (may exceed CAP)
        lc[i] = 0;
    }
    __syncthreads();
#pragma unroll
    for (int k = 0; k < NSLOT; ++k) {
        const unsigned t = tc[k];
        if (t >= NN) continue;
        const int bk = (int)(t >> 6);
        const unsigned pk = sc[k] | ((t & 63u) << 17);
        const int pos = hb[bk] + atomicAdd(&lc[bk], 1);
        if (pos < CAP) {
            packed[(size_t)bk * CAP + pos] = pk;
        } else {  // rare overflow: graceful spill
            const int sp = atomicAdd(gspill, 1);
            if (sp < SPILLCAP) { spill_pk[sp] = pk; spill_bk[sp] = (unsigned)bk; }
        }
    }
}

// x@W, lane=row, TWO waves per block splitting k (wave w: k in [32w,32w+32)).
// x staged in padded LDS [64][65]; W via wave-uniform scalar loads; k-loop
// unroll 4 (4 LDS reads + W s_load batches in flight). Partials combined via
// the freed xl. deg hist fused (region + spill), persisted to deg_g.
__global__ __launch_bounds__(128) void k_xw(const float* __restrict__ x,
                                            const float* __restrict__ W,
                                            const unsigned* __restrict__ packed,
                                            const int* __restrict__ gcur,
                                            const unsigned* __restrict__ spill_pk,
                                            const unsigned* __restrict__ spill_bk,
                                            const int* __restrict__ gspill,
                                            int* __restrict__ deg_g,
                                            __hip_bfloat16* __restrict__ xsh) {
    __shared__ float xl[64 * 65];   // 16.64 KB (x -> partials -> out-bounce)
    __shared__ int hist[64];
    const int tid = threadIdx.x;
    const int lane = tid & 63, kw = tid >> 6;  // lane = local row, kw = k-half
    const int b = blockIdx.x;       // bucket; rows [64b, 64b+64)
    const int row0 = b * 64;
    const int nrow = (NN - row0) < 64 ? (NN - row0) : 64;
    {   // stage x rows, coalesced float4 over 128 threads
        const float4* __restrict__ xg = (const float4*)(x + (size_t)row0 * 64);
        const int nf4 = nrow * 16;
        for (int i = tid; i < nf4; i += 128) {
            const int r = i >> 4, q = i & 15;
            *(float4*)&xl[r * 65 + 4 * q] = xg[i];
        }
    }
    if (tid < 64) hist[tid] = 0;
    __syncthreads();
    {   // degree hist: fixed region + spill (spill empty in practice)
        int cnt = gcur[b];
        cnt = (cnt < 0) ? 0 : (cnt > CAP ? CAP : cnt);
        const unsigned* __restrict__ seg = packed + (size_t)b * CAP;
        for (int i = tid; i < cnt; i += 128) atomicAdd(&hist[seg[i] >> 17], 1);
        int ns = *gspill;
        ns = (ns < 0) ? 0 : (ns > SPILLCAP ? SPILLCAP : ns);
        for (int i = tid; i < ns; i += 128)
            if ((int)spill_bk[i] == b) atomicAdd(&hist[(spill_pk[i] >> 17) & 63u], 1);
    }
    __syncthreads();
    const int myrow = row0 + lane;
    if (kw == 0 && myrow < NN) deg_g[myrow] = hist[lane];  // persist for k_sagg
    const float dv = rsqrtf(1.0f + (float)hist[lane]);
    float acc[64];
#pragma unroll
    for (int d = 0; d < 64; ++d) acc[d] = 0.0f;
    const int k0 = kw * 32;
#pragma unroll 4
    for (int kk = 0; kk < 32; ++kk) {
        const int k = k0 + kk;
        const float xv = xl[lane * 65 + k];  // per-lane, (lane+k)%32 banks
#pragma unroll
        for (int d = 0; d < 64; ++d)         // W[k*64+d] is wave-uniform ->
            acc[d] = fmaf(xv, W[k * 64 + d], acc[d]);  // s_load + SGPR FMA
    }
    __syncthreads();  // all xl reads done
    if (kw == 1) {    // wave 1 deposits its partials
#pragma unroll
        for (int d = 0; d < 64; ++d) xl[lane * 65 + d] = acc[d];
    }
    __syncthreads();
    unsigned* __restrict__ ol = (unsigned*)xl;  // pack target [64][33]
    if (kw == 0) {    // wave 0 combines + packs bf16 pairs
#pragma unroll
        for (int d = 0; d < 64; ++d) acc[d] += xl[lane * 65 + d];
        unsigned w[32];
#pragma unroll
        for (int q = 0; q < 32; ++q) {
            const __hip_bfloat16 b0 = __float2bfloat16(acc[2 * q] * dv);
            const __hip_bfloat16 b1 = __float2bfloat16(acc[2 * q + 1] * dv);
            w[q] = ((unsigned)*(const unsigned short*)&b1 << 16) |
                   *(const unsigned short*)&b0;
        }
        __syncthreads();  // partials consumed; safe to overwrite as ol
#pragma unroll
        for (int q = 0; q < 32; ++q) ol[lane * 33 + q] = w[q];
    } else {
        __syncthreads();  // match wave 0's barrier
    }
    __syncthreads();
    unsigned* __restrict__ og = (unsigned*)(xsh + (size_t)row0 * 64);
    const int nw = nrow * 32;
    for (int i = tid; i < nw; i += 128) {  // coalesced global store
        const int r = i >> 5, q = i & 31;
        og[i] = ol[r * 33 + q];
    }
}

// Fused per-HALF-bucket sort + NODE-PAIR aggregate + epilogue (R22-proven).
// Degrees from deg_g (coalesced). 2 blocks/bucket, 32 nodes each; 2 nodes per
// iter, 4 chains, 4 predicated uint2 loads in flight.
__global__ __launch_bounds__(256) void k_sagg(const unsigned* __restrict__ packed,
                                              const int* __restrict__ gcur,
                                              const unsigned* __restrict__ spill_pk,
                                              const unsigned* __restrict__ spill_bk,
                                              const int* __restrict__ gspill,
                                              const int* __restrict__ deg_g,
                                              const __hip_bfloat16* __restrict__ xsh,
                                              const float* __restrict__ bias,
                                              float* __restrict__ out) {
    __shared__ unsigned sorted[HCAP];  // 6 KB
    __shared__ int hist[32];
    __shared__ int pref[32];
    __shared__ int cur[32];
    __shared__ float sdinv[32];
    const int tid = threadIdx.x;
    const int b = blockIdx.x >> 1;         // bucket
    const unsigned half = blockIdx.x & 1;  // 0: tl 0..31, 1: tl 32..63
    int seg = gcur[b];
    seg = (seg < 0) ? 0 : (seg > CAP ? CAP : seg);
    const unsigned* __restrict__ region = packed + (size_t)b * CAP;
    int ns = *gspill;
    ns = (ns < 0) ? 0 : (ns > SPILLCAP ? SPILLCAP : ns);
    if (tid < 32) {  // degrees from k_xw (includes spill) — no region scan
        const int c = b * 64 + (int)half * 32 + tid;
        hist[tid] = (c < NN) ? deg_g[c] : 0;
    }
    __syncthreads();
    if (tid == 0) {
        int run = 0;
        for (int t = 0; t < 32; ++t) { pref[t] = run; run += hist[t]; }
    }
    __syncthreads();
    const int hcnt = pref[31] + hist[31];
    const bool oversize = (hcnt > HCAP);
    if (tid < 32) {
        cur[tid] = pref[tid];
        sdinv[tid] = rsqrtf(1.0f + (float)hist[tid]);
    }
    __syncthreads();
    if (!oversize) {
        for (int i = tid; i < seg; i += 256) {
            const unsigned pk = region[i];
            if (((pk >> 22) & 1u) == half) {
                const int pos = atomicAdd(&cur[(pk >> 17) & 31u], 1);
                if (pos < HCAP) sorted[pos] = pk & 0x1FFFFu;
            }
        }
        for (int i = tid; i < ns; i += 256) {  // spill: empty in practice
            if ((int)spill_bk[i] == b) {
                const unsigned pk = spill_pk[i];
                if (((pk >> 22) & 1u) == half) {
                    const int pos = atomicAdd(&cur[(pk >> 17) & 31u], 1);
                    if (pos < HCAP) sorted[pos] = pk & 0x1FFFFu;
                }
            }
        }
    }
    __syncthreads();

    const int wid = tid >> 6, lane = tid & 63;
    const int q = lane >> 4, sl = lane & 15;   // quarter, dim-quad
    const uint2* __restrict__ xs4 = (const uint2*)xsh;  // 4 bf16 per elem
    const float bv = bias[lane];
#pragma unroll 1
    for (int t = 0; t < 8; t += 2) {
        const int nlA = wid * 8 + t, nlB = nlA + 1;   // node pair
        const int cA = b * 64 + (int)half * 32 + nlA;
        const int cB = cA + 1;
        if (cA >= NN) break;               // wave-uniform
        const bool hasB = (cB < NN);       // wave-uniform
        const int offA = pref[nlA], offB = pref[nlB];
        int degA = hist[nlA];
        degA = (degA < 0) ? 0 : (degA > hcnt ? hcnt : degA);
        int degB = hasB ? hist[nlB] : 0;
        degB = (degB < 0) ? 0 : (degB > hcnt ? hcnt : degB);
        float4 a0A = {0.f,0.f,0.f,0.f}, a1A = {0.f,0.f,0.f,0.f};
        float4 a0B = {0.f,0.f,0.f,0.f}, a1B = {0.f,0.f,0.f,0.f};
        if (q == 0) {  // self-loop terms
            const uint2 vA = xs4[(size_t)cA * 16 + sl];
            UNPK4(vA, a0A)
            if (hasB) {
                const uint2 vB = xs4[(size_t)cB * 16 + sl];
                UNPK4(vB, a0B)
            }
        }
        if (!oversize) {
            const int dmax = (degA > degB) ? degA : degB;  // wave-uniform
            for (int j = 0; j < dmax; j += 8) {
                const int e0 = j + q, e1 = j + 4 + q;
                uint2 v0A = {0u,0u}, v1A = {0u,0u}, v0B = {0u,0u}, v1B = {0u,0u};
                if (e0 < degA) v0A = xs4[(size_t)sorted[offA + e0] * 16 + sl];
                if (e1 < degA) v1A = xs4[(size_t)sorted[offA + e1] * 16 + sl];
                if (e0 < degB) v0B = xs4[(size_t)sorted[offB + e0] * 16 + sl];
                if (e1 < degB) v1B = xs4[(size_t)sorted[offB + e1] * 16 + sl];
                UNPK4(v0A, a0A)
                UNPK4(v1A, a1A)
                UNPK4(v0B, a0B)
                UNPK4(v1B, a1B)
            }
        } else {  // scan-mode fallback: region + spill, tl-tagged (rare)
            if (q == 0) {
                const unsigned tlA = (unsigned)((int)half * 32 + nlA);
                const unsigned tlB = tlA + 1u;
                for (int i = 0; i < seg; ++i) {
                    const unsigned pk = region[i];
                    const unsigned tl = pk >> 17;
                    if (tl == tlA) {
                        const uint2 v = xs4[(size_t)(pk & 0x1FFFFu) * 16 + sl];
                        UNPK4(v, a0A)
                    }
                    if (hasB && tl == tlB) {
                        const uint2 v = xs4[(size_t)(pk & 0x1FFFFu) * 16 + sl];
                        UNPK4(v, a0B)
                    }
                }
                for (int i = 0; i < ns; ++i) {
                    if ((int)spill_bk[i] == b) {
                        const unsigned pk = spill_pk[i];
                        const unsigned tl = pk >> 17;
                        if (tl == tlA) {
                            const uint2 v = xs4[(size_t)(pk & 0x1FFFFu) * 16 + sl];
                            UNPK4(v, a0A)
                        }
                        if (hasB && tl == tlB) {
                            const uint2 v = xs4[(size_t)(pk & 0x1FFFFu) * 16 + sl];
                            UNPK4(v, a0B)
                        }
                    }
                }
            }
        }
        sagg_finish(a0A, a1A, lane, cA, sdinv[nlA], bv, out);
        if (hasB) sagg_finish(a0B, a1B, lane, cB, sdinv[nlB], bv, out);
    }
}

extern "C" void kernel_launch(void* const* d_in, const int* in_sizes, int n_in,
                              void* d_out, int out_size, void* d_ws, size_t ws_size,
                              hipStream_t stream) {
    const float* x  = (const float*)d_in[0];
    const float* W  = (const float*)d_in[1];
    const float* b  = (const float*)d_in[2];
    const int*   ei = (const int*)d_in[3];
    float* out = (float*)d_out;

    __hip_bfloat16* xsh = (__hip_bfloat16*)d_ws;              // bf16[NN*64]
    unsigned* packed = (unsigned*)(xsh + (size_t)NN * 64);    // u32[NBUCK*CAP]
    int* gcur = (int*)(packed + (size_t)NBUCK * CAP);         // i32[NBUCK]
    int* gspill = gcur + NBUCK;                               // i32[1]
    unsigned* spill_pk = (unsigned*)(gspill + 1);             // u32[SPILLCAP]
    unsigned* spill_bk = spill_pk + SPILLCAP;                 // u32[SPILLCAP]
    int* deg_g = (int*)(spill_bk + SPILLCAP);                 // i32[NN]

    hipMemsetAsync(gcur, 0, (NBUCK + 1) * sizeof(int), stream);
    k_p1<<<P1B, P1T, 0, stream>>>(ei, gcur, packed, spill_pk, spill_bk, gspill);
    k_xw<<<NBUCK, 128, 0, stream>>>(x, W, packed, gcur, spill_pk, spill_bk, gspill, deg_g, xsh);
    k_sagg<<<NBUCK * 2, 256, 0, stream>>>(packed, gcur, spill_pk, spill_bk, gspill, deg_g, xsh, b, out);
}

// Round 25
// 124.579 us; speedup vs baseline: 1.2250x; 1.2250x over previous
//
#include <hip/hip_runtime.h>
#include <hip/hip_bf16.h>

// GCNConv: one-pass fixed-capacity binning (64 tgts/bucket, CAP slots each) ->
// fused per-half-bucket {LDS counting sort + node-pair quarter-lane gather +
// epilogue}. No fp32 global atomics anywhere.
// agg[c] = dinv[c] * ( xs[c] + sum_{e: col[e]==c} xs[row[e]] ),
//   xs[i] = (x@W)[i] * dinv[i],  dinv[i] = rsqrt(1 + indeg(i))
// out = dropout(tanh(agg + b)), JAX partitionable-threefry key (0,42), p_keep=0.9:
//   bits[p] = o0^o1 of threefry((0,42), 0, p); u = bitcast(bits>>9|0x3f800000)-1; keep = u<0.9.
//
// R8: __shfl only in uniform regions (predicated regions contain loads only).
// R24 lesson (reverted): 2-wave k-split k_xw = 95us (SGPR budget can't hold
//   unrolled W rows). R23/R24 attribution: the R12/R18-form 256-thread wreg
//   k_xw (~33us, LDS-pipe bound) beats lane=row scalar-W (~50-54us) — R20
//   mis-credited its total win to the wrong kernel. R25 = R22 exactly, with
//   k_xw swapped back to the R18 form + deg_g persist.
//
// ws (~20.5 MB): xsh bf16[NN*64] | packed u32[NBUCK*CAP] | gcur i32[NBUCK] |
//                gspill i32[1] | spill_pk u32[SPILLCAP] | spill_bk u32[SPILLCAP] |
//                deg_g i32[NN]

#define NN 100000
#define NE 1600000
#define NBUCK 1563          // 64 tgts/bucket; bucket = tgt>>6
#define P1B 256
#define P1T 1024
#define CHUNK 6250          // P1B * CHUNK == NE
#define CAP 1152            // per-bucket region (mean 1024, +4 sigma)
#define SPILLCAP 16384
#define HCAP 1536           // per-half-bucket LDS sort capacity

// ---------------- Threefry2x32 (JAX-exact) ----------------
__device__ __forceinline__ unsigned rotl32(unsigned x, int r) {
    return (x << r) | (x >> (32 - r));
}

__device__ __forceinline__ void threefry2x32(unsigned k0, unsigned k1,
                                             unsigned x0, unsigned x1,
                                             unsigned& o0, unsigned& o1) {
    const unsigned ks0 = k0, ks1 = k1, ks2 = k0 ^ k1 ^ 0x1BD11BDAu;
    x0 += ks0; x1 += ks1;
    x0 += x1; x1 = rotl32(x1, 13); x1 ^= x0;
    x0 += x1; x1 = rotl32(x1, 15); x1 ^= x0;
    x0 += x1; x1 = rotl32(x1, 26); x1 ^= x0;
    x0 += x1; x1 = rotl32(x1, 6);  x1 ^= x0;
    x0 += ks1; x1 += ks2 + 1u;
    x0 += x1; x1 = rotl32(x1, 17); x1 ^= x0;
    x0 += x1; x1 = rotl32(x1, 29); x1 ^= x0;
    x0 += x1; x1 = rotl32(x1, 16); x1 ^= x0;
    x0 += x1; x1 = rotl32(x1, 24); x1 ^= x0;
    x0 += ks2; x1 += ks0 + 2u;
    x0 += x1; x1 = rotl32(x1, 13); x1 ^= x0;
    x0 += x1; x1 = rotl32(x1, 15); x1 ^= x0;
    x0 += x1; x1 = rotl32(x1, 26); x1 ^= x0;
    x0 += x1; x1 = rotl32(x1, 6);  x1 ^= x0;
    x0 += ks0; x1 += ks1 + 3u;
    x0 += x1; x1 = rotl32(x1, 17); x1 ^= x0;
    x0 += x1; x1 = rotl32(x1, 29); x1 ^= x0;
    x0 += x1; x1 = rotl32(x1, 16); x1 ^= x0;
    x0 += x1; x1 = rotl32(x1, 24); x1 ^= x0;
    x0 += ks1; x1 += ks2 + 4u;
    x0 += x1; x1 = rotl32(x1, 13); x1 ^= x0;
    x0 += x1; x1 = rotl32(x1, 15); x1 ^= x0;
    x0 += x1; x1 = rotl32(x1, 26); x1 ^= x0;
    x0 += x1; x1 = rotl32(x1, 6);  x1 ^= x0;
    x0 += ks2; x1 += ks0 + 5u;
    o0 = x0; o1 = x1;
}

// Per-node epilogue: quarter-reduce, redistribute, tanh + threefry dropout.
// Contains shfls — call ONLY under wave-uniform control flow.
__device__ __forceinline__ void sagg_finish(float4 a0, float4 a1, int lane,
                                            int c, float dv, float bv,
                                            float* __restrict__ out) {
    float ax = a0.x + a1.x, ay = a0.y + a1.y;
    float az = a0.z + a1.z, aw = a0.w + a1.w;
    ax += __shfl_xor(ax, 16); ax += __shfl_xor(ax, 32);
    ay += __shfl_xor(ay, 16); ay += __shfl_xor(ay, 32);
    az += __shfl_xor(az, 16); az += __shfl_xor(az, 32);
    aw += __shfl_xor(aw, 16); aw += __shfl_xor(aw, 32);
    const float sx = __shfl(ax, lane >> 2);
    const float sy = __shfl(ay, lane >> 2);
    const float sz = __shfl(az, lane >> 2);
    const float sw = __shfl(aw, lane >> 2);
    const float ab = (lane & 1) ? sy : sx;
    const float cd = (lane & 1) ? sw : sz;
    const float a = (lane & 2) ? cd : ab;
    const int p = c * 64 + lane;
    unsigned o0, o1;
    threefry2x32(0u, 42u, 0u, (unsigned)p, o0, o1);
    const unsigned bits = o0 ^ o1;
    const float u = __uint_as_float((bits >> 9) | 0x3f800000u) - 1.0f;
    const float h = tanhf(dv * a + bv);
    out[p] = (u < 0.9f) ? h / 0.9f : 0.0f;
}

#define UNPK4(v, A)                                                    \
    A.x += __uint_as_float((v).x << 16);                               \
    A.y += __uint_as_float((v).x & 0xffff0000u);                       \
    A.z += __uint_as_float((v).y << 16);                               \
    A.w += __uint_as_float((v).y & 0xffff0000u);

// ---------------- Kernels ----------------
// Binning: LDS hist -> one global reserve atomic per (block,bucket) ->
// grouped writes into fixed regions. Overflow -> spill list. (R22-proven.)
__global__ __launch_bounds__(P1T) void k_p1(const int* __restrict__ ei,
                                            int* __restrict__ gcur,
                                            unsigned* __restrict__ packed,
                                            unsigned* __restrict__ spill_pk,
                                            unsigned* __restrict__ spill_bk,
                                            int* __restrict__ gspill) {
    __shared__ int hb[NBUCK];
    __shared__ int lc[NBUCK];
    const int tid = threadIdx.x;
    for (int i = tid; i < NBUCK; i += P1T) { hb[i] = 0; lc[i] = 0; }
    __syncthreads();
    const int base = blockIdx.x * CHUNK;
    for (int i = tid; i < CHUNK; i += P1T) {
        const unsigned t = (unsigned)ei[NE + base + i];
        if (t < NN) atomicAdd(&hb[t >> 6], 1);
    }
    __syncthreads();
    for (int i = tid; i < NBUCK; i += P1T) {
        const int h = hb[i];
        hb[i] = h ? atomicAdd(&gcur[i], h) : 0;  // reserve (may exceed CAP)
        lc[i] = 0;
    }
    __syncthreads();
    for (int i = tid; i < CHUNK; i += P1T) {
        const unsigned t = (unsigned)ei[NE + base + i];
        if (t >= NN) continue;
        const unsigned src = (unsigned)ei[base + i];
        const int bk = t >> 6;
        const unsigned pk = src | ((t & 63u) << 17);
        const int pos = hb[bk] + atomicAdd(&lc[bk], 1);
        if (pos < CAP) {
            packed[(size_t)bk * CAP + pos] = pk;
        } else {  // rare overflow: graceful spill
            const int sp = atomicAdd(gspill, 1);
            if (sp < SPILLCAP) { spill_pk[sp] = pk; spill_bk[sp] = (unsigned)bk; }
        }
    }
}

// x@W (R18-form): 256 threads / 4 waves per bucket. W staged in LDS then
// transpose-read ONCE into 64 VGPRs (lane = output dim); x rows staged in LDS
// and distributed per-row via ds_read_b128 BROADCASTS (same-addr = free) +
// 64 register FMAs. Fused region-hist -> sdinv, persisted to deg_g.
__global__ __launch_bounds__(256) void k_xw(const float* __restrict__ x,
                                            const float* __restrict__ W,
                                            const unsigned* __restrict__ packed,
                                            const int* __restrict__ gcur,
                                            const unsigned* __restrict__ spill_pk,
                                            const unsigned* __restrict__ spill_bk,
                                            const int* __restrict__ gspill,
                                            int* __restrict__ deg_g,
                                            __hip_bfloat16* __restrict__ xsh) {
    __shared__ float Wl[64 * 64];   // 16 KB
    __shared__ float xl[64 * 64];   // 16 KB
    __shared__ int hist[64];
    __shared__ float sdinv[64];
    const int tid = threadIdx.x;
    const int b = blockIdx.x;       // grid == NBUCK
    const int row0 = b * 64;
    for (int i = tid; i < 64 * 64; i += 256) Wl[i] = W[i];  // coalesced
    {
        const int nrow = (NN - row0) < 64 ? (NN - row0) : 64;
        const int nfl4 = nrow * 16;
        const float4* __restrict__ xg = (const float4*)(x + (size_t)row0 * 64);
        float4* __restrict__ xl4 = (float4*)xl;
        for (int i = tid; i < nfl4; i += 256) xl4[i] = xg[i];
    }
    if (tid < 64) hist[tid] = 0;
    __syncthreads();
    {   // degree hist: fixed region + spill (spill empty in practice)
        int cnt = gcur[b];
        cnt = (cnt < 0) ? 0 : (cnt > CAP ? CAP : cnt);
        const unsigned* __restrict__ seg = packed + (size_t)b * CAP;
        for (int i = tid; i < cnt; i += 256) atomicAdd(&hist[seg[i] >> 17], 1);
        int ns = *gspill;
        ns = (ns < 0) ? 0 : (ns > SPILLCAP ? SPILLCAP : ns);
        for (int i = tid; i < ns; i += 256)
            if ((int)spill_bk[i] == b) atomicAdd(&hist[(spill_pk[i] >> 17) & 63u], 1);
    }
    __syncthreads();
    if (tid < 64) {
        sdinv[tid] = rsqrtf(1.0f + (float)hist[tid]);
        const int myrow = row0 + tid;
        if (myrow < NN) deg_g[myrow] = hist[tid];  // persist for k_sagg
    }
    __syncthreads();
    const int wid = tid >> 6, lane = tid & 63;
    float wreg[64];
#pragma unroll
    for (int k = 0; k < 64; ++k) wreg[k] = Wl[k * 64 + lane];  // W^T col -> regs
    const int rbase = wid * 16;
#pragma unroll 1
    for (int r = 0; r < 16; ++r) {
        const int row = row0 + rbase + r;
        if (row >= NN) break;  // wave-uniform
        const float4* __restrict__ xr4 = (const float4*)(xl + (rbase + r) * 64);
        float sum = 0.0f;
#pragma unroll
        for (int q = 0; q < 16; ++q) {
            const float4 xv = xr4[q];  // ds_read_b128 broadcast (same addr)
            sum = fmaf(xv.x, wreg[4 * q + 0], sum);
            sum = fmaf(xv.y, wreg[4 * q + 1], sum);
            sum = fmaf(xv.z, wreg[4 * q + 2], sum);
            sum = fmaf(xv.w, wreg[4 * q + 3], sum);
        }
        xsh[(size_t)row * 64 + lane] = __float2bfloat16(sum * sdinv[rbase + r]);
    }
}

// Fused per-HALF-bucket sort + NODE-PAIR aggregate + epilogue (R22-proven).
// Degrees from deg_g (coalesced). 2 blocks/bucket, 32 nodes each; 2 nodes per
// iter, 4 chains, 4 predicated uint2 loads in flight.
__global__ __launch_bounds__(256) void k_sagg(const unsigned* __restrict__ packed,
                                              const int* __restrict__ gcur,
                                              const unsigned* __restrict__ spill_pk,
                                              const unsigned* __restrict__ spill_bk,
                                              const int* __restrict__ gspill,
                                              const int* __restrict__ deg_g,
                                              const __hip_bfloat16* __restrict__ xsh,
                                              const float* __restrict__ bias,
                                              float* __restrict__ out) {
    __shared__ unsigned sorted[HCAP];  // 6 KB
    __shared__ int hist[32];
    __shared__ int pref[32];
    __shared__ int cur[32];
    __shared__ float sdinv[32];
    const int tid = threadIdx.x;
    const int b = blockIdx.x >> 1;         // bucket
    const unsigned half = blockIdx.x & 1;  // 0: tl 0..31, 1: tl 32..63
    int seg = gcur[b];
    seg = (seg < 0) ? 0 : (seg > CAP ? CAP : seg);
    const unsigned* __restrict__ region = packed + (size_t)b * CAP;
    int ns = *gspill;
    ns = (ns < 0) ? 0 : (ns > SPILLCAP ? SPILLCAP : ns);
    if (tid < 32) {  // degrees from k_xw (includes spill) — no region scan
        const int c = b * 64 + (int)half * 32 + tid;
        hist[tid] = (c < NN) ? deg_g[c] : 0;
    }
    __syncthreads();
    if (tid == 0) {
        int run = 0;
        for (int t = 0; t < 32; ++t) { pref[t] = run; run += hist[t]; }
    }
    __syncthreads();
    const int hcnt = pref[31] + hist[31];
    const bool oversize = (hcnt > HCAP);
    if (tid < 32) {
        cur[tid] = pref[tid];
        sdinv[tid] = rsqrtf(1.0f + (float)hist[tid]);
    }
    __syncthreads();
    if (!oversize) {
        for (int i = tid; i < seg; i += 256) {
            const unsigned pk = region[i];
            if (((pk >> 22) & 1u) == half) {
                const int pos = atomicAdd(&cur[(pk >> 17) & 31u], 1);
                if (pos < HCAP) sorted[pos] = pk & 0x1FFFFu;
            }
        }
        for (int i = tid; i < ns; i += 256) {  // spill: empty in practice
            if ((int)spill_bk[i] == b) {
                const unsigned pk = spill_pk[i];
                if (((pk >> 22) & 1u) == half) {
                    const int pos = atomicAdd(&cur[(pk >> 17) & 31u], 1);
                    if (pos < HCAP) sorted[pos] = pk & 0x1FFFFu;
                }
            }
        }
    }
    __syncthreads();

    const int wid = tid >> 6, lane = tid & 63;
    const int q = lane >> 4, sl = lane & 15;   // quarter, dim-quad
    const uint2* __restrict__ xs4 = (const uint2*)xsh;  // 4 bf16 per elem
    const float bv = bias[lane];
#pragma unroll 1
    for (int t = 0; t < 8; t += 2) {
        const int nlA = wid * 8 + t, nlB = nlA + 1;   // node pair
        const int cA = b * 64 + (int)half * 32 + nlA;
        const int cB = cA + 1;
        if (cA >= NN) break;               // wave-uniform
        const bool hasB = (cB < NN);       // wave-uniform
        const int offA = pref[nlA], offB = pref[nlB];
        int degA = hist[nlA];
        degA = (degA < 0) ? 0 : (degA > hcnt ? hcnt : degA);
        int degB = hasB ? hist[nlB] : 0;
        degB = (degB < 0) ? 0 : (degB > hcnt ? hcnt : degB);
        float4 a0A = {0.f,0.f,0.f,0.f}, a1A = {0.f,0.f,0.f,0.f};
        float4 a0B = {0.f,0.f,0.f,0.f}, a1B = {0.f,0.f,0.f,0.f};
        if (q == 0) {  // self-loop terms
            const uint2 vA = xs4[(size_t)cA * 16 + sl];
            UNPK4(vA, a0A)
            if (hasB) {
                const uint2 vB = xs4[(size_t)cB * 16 + sl];
                UNPK4(vB, a0B)
            }
        }
        if (!oversize) {
            const int dmax = (degA > degB) ? degA : degB;  // wave-uniform
            for (int j = 0; j < dmax; j += 8) {
                const int e0 = j + q, e1 = j + 4 + q;
                uint2 v0A = {0u,0u}, v1A = {0u,0u}, v0B = {0u,0u}, v1B = {0u,0u};
                if (e0 < degA) v0A = xs4[(size_t)sorted[offA + e0] * 16 + sl];
                if (e1 < degA) v1A = xs4[(size_t)sorted[offA + e1] * 16 + sl];
                if (e0 < degB) v0B = xs4[(size_t)sorted[offB + e0] * 16 + sl];
                if (e1 < degB) v1B = xs4[(size_t)sorted[offB + e1] * 16 + sl];
                UNPK4(v0A, a0A)
                UNPK4(v1A, a1A)
                UNPK4(v0B, a0B)
                UNPK4(v1B, a1B)
            }
        } else {  // scan-mode fallback: region + spill, tl-tagged (rare)
            if (q == 0) {
                const unsigned tlA = (unsigned)((int)half * 32 + nlA);
                const unsigned tlB = tlA + 1u;
                for (int i = 0; i < seg; ++i) {
                    const unsigned pk = region[i];
                    const unsigned tl = pk >> 17;
                    if (tl == tlA) {
                        const uint2 v = xs4[(size_t)(pk & 0x1FFFFu) * 16 + sl];
                        UNPK4(v, a0A)
                    }
                    if (hasB && tl == tlB) {
                        const uint2 v = xs4[(size_t)(pk & 0x1FFFFu) * 16 + sl];
                        UNPK4(v, a0B)
                    }
                }
                for (int i = 0; i < ns; ++i) {
                    if ((int)spill_bk[i] == b) {
                        const unsigned pk = spill_pk[i];
                        const unsigned tl = pk >> 17;
                        if (tl == tlA) {
                            const uint2 v = xs4[(size_t)(pk & 0x1FFFFu) * 16 + sl];
                            UNPK4(v, a0A)
                        }
                        if (hasB && tl == tlB) {
                            const uint2 v = xs4[(size_t)(pk & 0x1FFFFu) * 16 + sl];
                            UNPK4(v, a0B)
                        }
                    }
                }
            }
        }
        sagg_finish(a0A, a1A, lane, cA, sdinv[nlA], bv, out);
        if (hasB) sagg_finish(a0B, a1B, lane, cB, sdinv[nlB], bv, out);
    }
}

extern "C" void kernel_launch(void* const* d_in, const int* in_sizes, int n_in,
                              void* d_out, int out_size, void* d_ws, size_t ws_size,
                              hipStream_t stream) {
    const float* x  = (const float*)d_in[0];
    const float* W  = (const float*)d_in[1];
    const float* b  = (const float*)d_in[2];
    const int*   ei = (const int*)d_in[3];
    float* out = (float*)d_out;

    __hip_bfloat16* xsh = (__hip_bfloat16*)d_ws;              // bf16[NN*64]
    unsigned* packed = (unsigned*)(xsh + (size_t)NN * 64);    // u32[NBUCK*CAP]
    int* gcur = (int*)(packed + (size_t)NBUCK * CAP);         // i32[NBUCK]
    int* gspill = gcur + NBUCK;                               // i32[1]
    unsigned* spill_pk = (unsigned*)(gspill + 1);             // u32[SPILLCAP]
    unsigned* spill_bk = spill_pk + SPILLCAP;                 // u32[SPILLCAP]
    int* deg_g = (int*)(spill_bk + SPILLCAP);                 // i32[NN]

    hipMemsetAsync(gcur, 0, (NBUCK + 1) * sizeof(int), stream);
    k_p1<<<P1B, P1T, 0, stream>>>(ei, gcur, packed, spill_pk, spill_bk, gspill);
    k_xw<<<NBUCK, 256, 0, stream>>>(x, W, packed, gcur, spill_pk, spill_bk, gspill, deg_g, xsh);
    k_sagg<<<NBUCK * 2, 256, 0, stream>>>(packed, gcur, spill_pk, spill_bk, gspill, deg_g, xsh, b, out);
}

// Round 26
// 89.382 us; speedup vs baseline: 1.7073x; 1.3938x over previous
//
#include <hip/hip_runtime.h>
#include <hip/hip_bf16.h>

// GCNConv: one-pass fixed-capacity binning (64 tgts/bucket) -> MFMA x@W ->
// fused per-half-bucket {LDS counting sort + node-pair gather + epilogue}.
// agg[c] = dinv[c] * ( xs[c] + sum_{e: col[e]==c} xs[row[e]] ),
//   xs[i] = (x@W)[i] * dinv[i],  dinv[i] = rsqrt(1 + indeg(i))
// out = dropout(tanh(agg + b)), JAX partitionable-threefry key (0,42), p_keep=0.9.
//
// R25 lesson: all VALU GEMM forms are LDS/latency-bound at 50-95us (the m97
//   ladder's lesson: matmul-shaped work belongs on MFMA). R26: k_xw uses
//   mfma_f32_16x16x32_bf16; x/W^T staged bf16 in XOR-swizzled LDS (G4:
//   byte ^= (row&7)<<4 kills the 128B-stride 16-way conflict); C/D mapping
//   col=lane&15, row=(lane>>4)*4+reg (guide-verified m89/m91).
//
// ws (~20.5 MB): xsh bf16[NN*64] | packed u32[NBUCK*CAP] | gcur i32[NBUCK] |
//                gspill i32[1] | spill_pk u32[SPILLCAP] | spill_bk u32[SPILLCAP] |
//                deg_g i32[NN]

#define NN 100000
#define NE 1600000
#define NBUCK 1563          // 64 tgts/bucket; bucket = tgt>>6
#define P1B 256
#define P1T 1024
#define CHUNK 6250          // P1B * CHUNK == NE
#define CAP 1152            // per-bucket region (mean 1024, +4 sigma)
#define SPILLCAP 16384
#define HCAP 1536           // per-half-bucket LDS sort capacity

typedef __attribute__((ext_vector_type(8))) short bf8;   // 8 bf16 (4 VGPR)
typedef __attribute__((ext_vector_type(4))) float f32x4; // MFMA acc

// ---------------- Threefry2x32 (JAX-exact) ----------------
__device__ __forceinline__ unsigned rotl32(unsigned x, int r) {
    return (x << r) | (x >> (32 - r));
}

__device__ __forceinline__ void threefry2x32(unsigned k0, unsigned k1,
                                             unsigned x0, unsigned x1,
                                             unsigned& o0, unsigned& o1) {
    const unsigned ks0 = k0, ks1 = k1, ks2 = k0 ^ k1 ^ 0x1BD11BDAu;
    x0 += ks0; x1 += ks1;
    x0 += x1; x1 = rotl32(x1, 13); x1 ^= x0;
    x0 += x1; x1 = rotl32(x1, 15); x1 ^= x0;
    x0 += x1; x1 = rotl32(x1, 26); x1 ^= x0;
    x0 += x1; x1 = rotl32(x1, 6);  x1 ^= x0;
    x0 += ks1; x1 += ks2 + 1u;
    x0 += x1; x1 = rotl32(x1, 17); x1 ^= x0;
    x0 += x1; x1 = rotl32(x1, 29); x1 ^= x0;
    x0 += x1; x1 = rotl32(x1, 16); x1 ^= x0;
    x0 += x1; x1 = rotl32(x1, 24); x1 ^= x0;
    x0 += ks2; x1 += ks0 + 2u;
    x0 += x1; x1 = rotl32(x1, 13); x1 ^= x0;
    x0 += x1; x1 = rotl32(x1, 15); x1 ^= x0;
    x0 += x1; x1 = rotl32(x1, 26); x1 ^= x0;
    x0 += x1; x1 = rotl32(x1, 6);  x1 ^= x0;
    x0 += ks0; x1 += ks1 + 3u;
    x0 += x1; x1 = rotl32(x1, 17); x1 ^= x0;
    x0 += x1; x1 = rotl32(x1, 29); x1 ^= x0;
    x0 += x1; x1 = rotl32(x1, 16); x1 ^= x0;
    x0 += x1; x1 = rotl32(x1, 24); x1 ^= x0;
    x0 += ks1; x1 += ks2 + 4u;
    x0 += x1; x1 = rotl32(x1, 13); x1 ^= x0;
    x0 += x1; x1 = rotl32(x1, 15); x1 ^= x0;
    x0 += x1; x1 = rotl32(x1, 26); x1 ^= x0;
    x0 += x1; x1 = rotl32(x1, 6);  x1 ^= x0;
    x0 += ks2; x1 += ks0 + 5u;
    o0 = x0; o1 = x1;
}

// Per-node epilogue: quarter-reduce, redistribute, tanh + threefry dropout.
// Contains shfls — call ONLY under wave-uniform control flow.
__device__ __forceinline__ void sagg_finish(float4 a0, float4 a1, int lane,
                                            int c, float dv, float bv,
                                            float* __restrict__ out) {
    float ax = a0.x + a1.x, ay = a0.y + a1.y;
    float az = a0.z + a1.z, aw = a0.w + a1.w;
    ax += __shfl_xor(ax, 16); ax += __shfl_xor(ax, 32);
    ay += __shfl_xor(ay, 16); ay += __shfl_xor(ay, 32);
    az += __shfl_xor(az, 16); az += __shfl_xor(az, 32);
    aw += __shfl_xor(aw, 16); aw += __shfl_xor(aw, 32);
    const float sx = __shfl(ax, lane >> 2);
    const float sy = __shfl(ay, lane >> 2);
    const float sz = __shfl(az, lane >> 2);
    const float sw = __shfl(aw, lane >> 2);
    const float ab = (lane & 1) ? sy : sx;
    const float cd = (lane & 1) ? sw : sz;
    const float a = (lane & 2) ? cd : ab;
    const int p = c * 64 + lane;
    unsigned o0, o1;
    threefry2x32(0u, 42u, 0u, (unsigned)p, o0, o1);
    const unsigned bits = o0 ^ o1;
    const float u = __uint_as_float((bits >> 9) | 0x3f800000u) - 1.0f;
    const float h = tanhf(dv * a + bv);
    out[p] = (u < 0.9f) ? h / 0.9f : 0.0f;
}

#define UNPK4(v, A)                                                    \
    A.x += __uint_as_float((v).x << 16);                               \
    A.y += __uint_as_float((v).x & 0xffff0000u);                       \
    A.z += __uint_as_float((v).y << 16);                               \
    A.w += __uint_as_float((v).y & 0xffff0000u);

// ---------------- Kernels ----------------
// Binning: LDS hist -> one global reserve atomic per (block,bucket) ->
// grouped writes into fixed regions. Overflow -> spill list. (R22-proven.)
__global__ __launch_bounds__(P1T) void k_p1(const int* __restrict__ ei,
                                            int* __restrict__ gcur,
                                            unsigned* __restrict__ packed,
                                            unsigned* __restrict__ spill_pk,
                                            unsigned* __restrict__ spill_bk,
                                            int* __restrict__ gspill) {
    __shared__ int hb[NBUCK];
    __shared__ int lc[NBUCK];
    const int tid = threadIdx.x;
    for (int i = tid; i < NBUCK; i += P1T) { hb[i] = 0; lc[i] = 0; }
    __syncthreads();
    const int base = blockIdx.x * CHUNK;
    for (int i = tid; i < CHUNK; i += P1T) {
        const unsigned t = (unsigned)ei[NE + base + i];
        if (t < NN) atomicAdd(&hb[t >> 6], 1);
    }
    __syncthreads();
    for (int i = tid; i < NBUCK; i += P1T) {
        const int h = hb[i];
        hb[i] = h ? atomicAdd(&gcur[i], h) : 0;  // reserve (may exceed CAP)
        lc[i] = 0;
    }
    __syncthreads();
    for (int i = tid; i < CHUNK; i += P1T) {
        const unsigned t = (unsigned)ei[NE + base + i];
        if (t >= NN) continue;
        const unsigned src = (unsigned)ei[base + i];
        const int bk = t >> 6;
        const unsigned pk = src | ((t & 63u) << 17);
        const int pos = hb[bk] + atomicAdd(&lc[bk], 1);
        if (pos < CAP) {
            packed[(size_t)bk * CAP + pos] = pk;
        } else {  // rare overflow: graceful spill
            const int sp = atomicAdd(gspill, 1);
            if (sp < SPILLCAP) { spill_pk[sp] = pk; spill_bk[sp] = (unsigned)bk; }
        }
    }
}

// x@W via MFMA: 256 threads / 4 waves per bucket (64 rows). x and W^T staged
// as bf16 in XOR-swizzled LDS; each wave computes a 16x64 stripe with 8
// mfma_f32_16x16x32_bf16. Fused region-hist -> sdinv + deg_g persist.
// Epilogue bounces C through LDS for coalesced bf16 stores.
__global__ __launch_bounds__(256) void k_xw(const float* __restrict__ x,
                                            const float* __restrict__ W,
                                            const unsigned* __restrict__ packed,
                                            const int* __restrict__ gcur,
                                            const unsigned* __restrict__ spill_pk,
                                            const unsigned* __restrict__ spill_bk,
                                            const int* __restrict__ gspill,
                                            int* __restrict__ deg_g,
                                            __hip_bfloat16* __restrict__ xsh) {
    __shared__ unsigned short xbf[64 * 64];  // 8 KB, swizzled; reused as bounce
    __shared__ unsigned short wb[64 * 64];   // 8 KB, swizzled W^T (wb[d][k])
    __shared__ int hist[64];
    __shared__ float sdinv[64];
    const int tid = threadIdx.x;
    const int b = blockIdx.x;       // grid == NBUCK
    const int row0 = b * 64;
    const int nrow = (NN - row0) < 64 ? (NN - row0) : 64;
    // stage x -> bf16, swizzled: byte = (r*128 + cp*4) ^ ((r&7)<<4)
    for (int i = tid; i < 64 * 32; i += 256) {
        const int r = i >> 5, cp = i & 31;  // cols 2cp, 2cp+1
        unsigned v = 0u;
        if (r < nrow) {
            const float2 xv = *(const float2*)(x + (size_t)(row0 + r) * 64 + 2 * cp);
            const __hip_bfloat16 b0 = __float2bfloat16(xv.x);
            const __hip_bfloat16 b1 = __float2bfloat16(xv.y);
            v = ((unsigned)*(const unsigned short*)&b1 << 16) |
                *(const unsigned short*)&b0;
        }
        *(unsigned*)((char*)xbf + ((r * 128 + cp * 4) ^ ((r & 7) << 4))) = v;
    }
    // stage W^T -> bf16, swizzled: wb[d][k]; byte = (d*128 + k*2) ^ ((d&7)<<4)
    for (int i = tid; i < 64 * 64; i += 256) {
        const int k = i >> 6, d = i & 63;   // coalesced W read
        const __hip_bfloat16 wv = __float2bfloat16(W[i]);
        *(unsigned short*)((char*)wb + ((d * 128 + k * 2) ^ ((d & 7) << 4))) =
            *(const unsigned short*)&wv;
    }
    if (tid < 64) hist[tid] = 0;
    __syncthreads();
    {   // degree hist: fixed region + spill (spill empty in practice)
        int cnt = gcur[b];
        cnt = (cnt < 0) ? 0 : (cnt > CAP ? CAP : cnt);
        const unsigned* __restrict__ seg = packed + (size_t)b * CAP;
        for (int i = tid; i < cnt; i += 256) atomicAdd(&hist[seg[i] >> 17], 1);
        int ns = *gspill;
        ns = (ns < 0) ? 0 : (ns > SPILLCAP ? SPILLCAP : ns);
        for (int i = tid; i < ns; i += 256)
            if ((int)spill_bk[i] == b) atomicAdd(&hist[(spill_pk[i] >> 17) & 63u], 1);
    }
    __syncthreads();
    if (tid < 64) {
        sdinv[tid] = rsqrtf(1.0f + (float)hist[tid]);
        const int myrow = row0 + tid;
        if (myrow < NN) deg_g[myrow] = hist[tid];  // persist for k_sagg
    }
    const int wid = tid >> 6, lane = tid & 63;
    const int m = lane & 15, kg = lane >> 4;  // in-tile row/col, k-group
    f32x4 acc0 = {0.f, 0.f, 0.f, 0.f}, acc1 = {0.f, 0.f, 0.f, 0.f};
    f32x4 acc2 = {0.f, 0.f, 0.f, 0.f}, acc3 = {0.f, 0.f, 0.f, 0.f};
    const int arow = wid * 16 + m;
#pragma unroll
    for (int kk = 0; kk < 2; ++kk) {
        const int kbase = (kg * 8 + kk * 32) * 2;  // byte offset of k-slice
        const bf8 af = *(const bf8*)((const char*)xbf +
                                     ((arow * 128 + kbase) ^ ((arow & 7) << 4)));
        const int d0 = 0 * 16 + m, d1 = 1 * 16 + m, d2 = 2 * 16 + m, d3 = 3 * 16 + m;
        const bf8 bf0 = *(const bf8*)((const char*)wb +
                                      ((d0 * 128 + kbase) ^ ((d0 & 7) << 4)));
        const bf8 bf1 = *(const bf8*)((const char*)wb +
                                      ((d1 * 128 + kbase) ^ ((d1 & 7) << 4)));
        const bf8 bf2 = *(const bf8*)((const char*)wb +
                                      ((d2 * 128 + kbase) ^ ((d2 & 7) << 4)));
        const bf8 bf3 = *(const bf8*)((const char*)wb +
                                      ((d3 * 128 + kbase) ^ ((d3 & 7) << 4)));
        acc0 = __builtin_amdgcn_mfma_f32_16x16x32_bf16(af, bf0, acc0, 0, 0, 0);
        acc1 = __builtin_amdgcn_mfma_f32_16x16x32_bf16(af, bf1, acc1, 0, 0, 0);
        acc2 = __builtin_amdgcn_mfma_f32_16x16x32_bf16(af, bf2, acc2, 0, 0, 0);
        acc3 = __builtin_amdgcn_mfma_f32_16x16x32_bf16(af, bf3, acc3, 0, 0, 0);
    }
    __syncthreads();  // all frag reads done; xbf reusable as plain bounce
    // C/D: col = lane&15 (=m), row = (lane>>4)*4 + j (=kg*4+j) within tile.
#pragma unroll
    for (int j = 0; j < 4; ++j) {
        const int r = wid * 16 + kg * 4 + j;
        const float dv = sdinv[r];
        const float v0 = acc0[j] * dv, v1 = acc1[j] * dv;
        const float v2 = acc2[j] * dv, v3 = acc3[j] * dv;
        const __hip_bfloat16 h0 = __float2bfloat16(v0);
        const __hip_bfloat16 h1 = __float2bfloat16(v1);
        const __hip_bfloat16 h2 = __float2bfloat16(v2);
        const __hip_bfloat16 h3 = __float2bfloat16(v3);
        xbf[r * 64 + 0 * 16 + m]  = *(const unsigned short*)&h0;
        xbf[r * 64 + 1 * 16 + m]  = *(const unsigned short*)&h1;
        xbf[r * 64 + 2 * 16 + m]  = *(const unsigned short*)&h2;
        xbf[r * 64 + 3 * 16 + m]  = *(const unsigned short*)&h3;
    }
    __syncthreads();
    {   // coalesced copy out (nrow rows x 64 bf16 = nrow*8 uint4)
        const uint4* __restrict__ src = (const uint4*)xbf;
        uint4* __restrict__ dst = (uint4*)(xsh + (size_t)row0 * 64);
        const int n16 = nrow * 8;
        for (int i = tid; i < n16; i += 256) dst[i] = src[i];
    }
}

// Fused per-HALF-bucket sort + NODE-PAIR aggregate + epilogue (R22-proven).
// Degrees from deg_g (coalesced). 2 blocks/bucket, 32 nodes each; 2 nodes per
// iter, 4 chains, 4 predicated uint2 loads in flight.
__global__ __launch_bounds__(256) void k_sagg(const unsigned* __restrict__ packed,
                                              const int* __restrict__ gcur,
                                              const unsigned* __restrict__ spill_pk,
                                              const unsigned* __restrict__ spill_bk,
                                              const int* __restrict__ gspill,
                                              const int* __restrict__ deg_g,
                                              const __hip_bfloat16* __restrict__ xsh,
                                              const float* __restrict__ bias,
                                              float* __restrict__ out) {
    __shared__ unsigned sorted[HCAP];  // 6 KB
    __shared__ int hist[32];
    __shared__ int pref[32];
    __shared__ int cur[32];
    __shared__ float sdinv[32];
    const int tid = threadIdx.x;
    const int b = blockIdx.x >> 1;         // bucket
    const unsigned half = blockIdx.x & 1;  // 0: tl 0..31, 1: tl 32..63
    int seg = gcur[b];
    seg = (seg < 0) ? 0 : (seg > CAP ? CAP : seg);
    const unsigned* __restrict__ region = packed + (size_t)b * CAP;
    int ns = *gspill;
    ns = (ns < 0) ? 0 : (ns > SPILLCAP ? SPILLCAP : ns);
    if (tid < 32) {  // degrees from k_xw (includes spill) — no region scan
        const int c = b * 64 + (int)half * 32 + tid;
        hist[tid] = (c < NN) ? deg_g[c] : 0;
    }
    __syncthreads();
    if (tid == 0) {
        int run = 0;
        for (int t = 0; t < 32; ++t) { pref[t] = run; run += hist[t]; }
    }
    __syncthreads();
    const int hcnt = pref[31] + hist[31];
    const bool oversize = (hcnt > HCAP);
    if (tid < 32) {
        cur[tid] = pref[tid];
        sdinv[tid] = rsqrtf(1.0f + (float)hist[tid]);
    }
    __syncthreads();
    if (!oversize) {
        for (int i = tid; i < seg; i += 256) {
            const unsigned pk = region[i];
            if (((pk >> 22) & 1u) == half) {
                const int pos = atomicAdd(&cur[(pk >> 17) & 31u], 1);
                if (pos < HCAP) sorted[pos] = pk & 0x1FFFFu;
            }
        }
        for (int i = tid; i < ns; i += 256) {  // spill: empty in practice
            if ((int)spill_bk[i] == b) {
                const unsigned pk = spill_pk[i];
                if (((pk >> 22) & 1u) == half) {
                    const int pos = atomicAdd(&cur[(pk >> 17) & 31u], 1);
                    if (pos < HCAP) sorted[pos] = pk & 0x1FFFFu;
                }
            }
        }
    }
    __syncthreads();

    const int wid = tid >> 6, lane = tid & 63;
    const int q = lane >> 4, sl = lane & 15;   // quarter, dim-quad
    const uint2* __restrict__ xs4 = (const uint2*)xsh;  // 4 bf16 per elem
    const float bv = bias[lane];
#pragma unroll 1
    for (int t = 0; t < 8; t += 2) {
        const int nlA = wid * 8 + t, nlB = nlA + 1;   // node pair
        const int cA = b * 64 + (int)half * 32 + nlA;
        const int cB = cA + 1;
        if (cA >= NN) break;               // wave-uniform
        const bool hasB = (cB < NN);       // wave-uniform
        const int offA = pref[nlA], offB = pref[nlB];
        int degA = hist[nlA];
        degA = (degA < 0) ? 0 : (degA > hcnt ? hcnt : degA);
        int degB = hasB ? hist[nlB] : 0;
        degB = (degB < 0) ? 0 : (degB > hcnt ? hcnt : degB);
        float4 a0A = {0.f,0.f,0.f,0.f}, a1A = {0.f,0.f,0.f,0.f};
        float4 a0B = {0.f,0.f,0.f,0.f}, a1B = {0.f,0.f,0.f,0.f};
        if (q == 0) {  // self-loop terms
            const uint2 vA = xs4[(size_t)cA * 16 + sl];
            UNPK4(vA, a0A)
            if (hasB) {
                const uint2 vB = xs4[(size_t)cB * 16 + sl];
                UNPK4(vB, a0B)
            }
        }
        if (!oversize) {
            const int dmax = (degA > degB) ? degA : degB;  // wave-uniform
            for (int j = 0; j < dmax; j += 8) {
                const int e0 = j + q, e1 = j + 4 + q;
                uint2 v0A = {0u,0u}, v1A = {0u,0u}, v0B = {0u,0u}, v1B = {0u,0u};
                if (e0 < degA) v0A = xs4[(size_t)sorted[offA + e0] * 16 + sl];
                if (e1 < degA) v1A = xs4[(size_t)sorted[offA + e1] * 16 + sl];
                if (e0 < degB) v0B = xs4[(size_t)sorted[offB + e0] * 16 + sl];
                if (e1 < degB) v1B = xs4[(size_t)sorted[offB + e1] * 16 + sl];
                UNPK4(v0A, a0A)
                UNPK4(v1A, a1A)
                UNPK4(v0B, a0B)
                UNPK4(v1B, a1B)
            }
        } else {  // scan-mode fallback: region + spill, tl-tagged (rare)
            if (q == 0) {
                const unsigned tlA = (unsigned)((int)half * 32 + nlA);
                const unsigned tlB = tlA + 1u;
                for (int i = 0; i < seg; ++i) {
                    const unsigned pk = region[i];
                    const unsigned tl = pk >> 17;
                    if (tl == tlA) {
                        const uint2 v = xs4[(size_t)(pk & 0x1FFFFu) * 16 + sl];
                        UNPK4(v, a0A)
                    }
                    if (hasB && tl == tlB) {
                        const uint2 v = xs4[(size_t)(pk & 0x1FFFFu) * 16 + sl];
                        UNPK4(v, a0B)
                    }
                }
                for (int i = 0; i < ns; ++i) {
                    if ((int)spill_bk[i] == b) {
                        const unsigned pk = spill_pk[i];
                        const unsigned tl = pk >> 17;
                        if (tl == tlA) {
                            const uint2 v = xs4[(size_t)(pk & 0x1FFFFu) * 16 + sl];
                            UNPK4(v, a0A)
                        }
                        if (hasB && tl == tlB) {
                            const uint2 v = xs4[(size_t)(pk & 0x1FFFFu) * 16 + sl];
                            UNPK4(v, a0B)
                        }
                    }
                }
            }
        }
        sagg_finish(a0A, a1A, lane, cA, sdinv[nlA], bv, out);
        if (hasB) sagg_finish(a0B, a1B, lane, cB, sdinv[nlB], bv, out);
    }
}

extern "C" void kernel_launch(void* const* d_in, const int* in_sizes, int n_in,
                              void* d_out, int out_size, void* d_ws, size_t ws_size,
                              hipStream_t stream) {
    const float* x  = (const float*)d_in[0];
    const float* W  = (const float*)d_in[1];
    const float* b  = (const float*)d_in[2];
    const int*   ei = (const int*)d_in[3];
    float* out = (float*)d_out;

    __hip_bfloat16* xsh = (__hip_bfloat16*)d_ws;              // bf16[NN*64]
    unsigned* packed = (unsigned*)(xsh + (size_t)NN * 64);    // u32[NBUCK*CAP]
    int* gcur = (int*)(packed + (size_t)NBUCK * CAP);         // i32[NBUCK]
    int* gspill = gcur + NBUCK;                               // i32[1]
    unsigned* spill_pk = (unsigned*)(gspill + 1);             // u32[SPILLCAP]
    unsigned* spill_bk = spill_pk + SPILLCAP;                 // u32[SPILLCAP]
    int* deg_g = (int*)(spill_bk + SPILLCAP);                 // i32[NN]

    hipMemsetAsync(gcur, 0, (NBUCK + 1) * sizeof(int), stream);
    k_p1<<<P1B, P1T, 0, stream>>>(ei, gcur, packed, spill_pk, spill_bk, gspill);
    k_xw<<<NBUCK, 256, 0, stream>>>(x, W, packed, gcur, spill_pk, spill_bk, gspill, deg_g, xsh);
    k_sagg<<<NBUCK * 2, 256, 0, stream>>>(packed, gcur, spill_pk, spill_bk, gspill, deg_g, xsh, b, out);
}